// Round 9
// baseline (188.809 us; speedup 1.0000x reference)
//
#include <hip/hip_runtime.h>
#include <hip/hip_bf16.h>

#define B_ 2
#define T_ 2048
#define C_ 1024
#define H_ 16
#define D_ 64

typedef __attribute__((ext_vector_type(8))) short bf16x8;
typedef __attribute__((ext_vector_type(4))) float f32x4;

static __device__ __forceinline__ float bf2f(unsigned short u) {
  union { unsigned int i; float f; } c;
  c.i = ((unsigned int)u) << 16;
  return c.f;
}
static __device__ __forceinline__ unsigned short f2bf(float f) {
  union { float f; unsigned int i; } c;
  c.f = f;
  unsigned int x = c.i;
  return (unsigned short)((x + 0x7fffu + ((x >> 16) & 1u)) >> 16);  // RNE
}

// async global->LDS, 16B per lane; LDS dest = (wave-uniform base) + lane*16
static __device__ __forceinline__ void gl_lds16(const void* g, void* s) {
  __builtin_amdgcn_global_load_lds(
      (const __attribute__((address_space(1))) void*)g,
      (__attribute__((address_space(3))) void*)s, 16, 0, 0);
}

// ---------------------------------------------------------------------------
__global__ __launch_bounds__(256) void fill_kernel_f32(float* __restrict__ out,
                                                       int n, float v) {
  int i = blockIdx.x * 256 + threadIdx.x;
  if (i < n) out[i] = v;
}

// ---------------------------------------------------------------------------
// Fused prep:
//   z=0: w_attn [1024][3072] -> waT [3072][1024] bf16   (96x32 tiles)
//   z=1: w_proj [1024][1024] -> wpT [1024][1024] bf16
//   z=2: x fp32 -> xb bf16, 8 elems/thread
// ---------------------------------------------------------------------------
__global__ __launch_bounds__(256) void prep_kernel(
    const float* __restrict__ w_attn, const float* __restrict__ w_proj,
    const float* __restrict__ x,
    unsigned short* __restrict__ waT, unsigned short* __restrict__ wpT,
    unsigned short* __restrict__ xb) {
  __shared__ float tile[32][33];
  const int z = blockIdx.z;
  if (z == 2) {
    const int id = blockIdx.y * 96 + blockIdx.x;
    if (id >= 2048) return;
    int i = (id * 256 + threadIdx.x) * 8;
    float4 f0 = *(const float4*)(x + i);
    float4 f1 = *(const float4*)(x + i + 4);
    union { unsigned short u[8]; uint4 v; } p;
    p.u[0] = f2bf(f0.x); p.u[1] = f2bf(f0.y); p.u[2] = f2bf(f0.z); p.u[3] = f2bf(f0.w);
    p.u[4] = f2bf(f1.x); p.u[5] = f2bf(f1.y); p.u[6] = f2bf(f1.z); p.u[7] = f2bf(f1.w);
    *(uint4*)(xb + i) = p.v;
    return;
  }
  const float* W;
  unsigned short* WT;
  int Kd, Nd;
  if (z == 0) { W = w_attn; WT = waT; Kd = 1024; Nd = 3072; }
  else {
    if (blockIdx.x >= 32) return;
    W = w_proj; WT = wpT; Kd = 1024; Nd = 1024;
  }
  const int n0 = blockIdx.x * 32, k0 = blockIdx.y * 32;
  const int tx = threadIdx.x & 31, ty = threadIdx.x >> 5;  // ty 0..7
#pragma unroll
  for (int i = 0; i < 4; ++i)
    tile[ty + i * 8][tx] = W[(size_t)(k0 + ty + i * 8) * Nd + n0 + tx];
  __syncthreads();
#pragma unroll
  for (int i = 0; i < 4; ++i)
    WT[(size_t)(n0 + ty + i * 8) * Kd + k0 + tx] = f2bf(tile[tx][ty + i * 8]);
}

// ---------------------------------------------------------------------------
// Per-head V transpose: vP[b*T+t][h*64+d] -> vT[((b*16+h)*64+d)*2048 + t].
// ---------------------------------------------------------------------------
__global__ __launch_bounds__(256) void v_transpose(const unsigned short* __restrict__ vP,
                                                   unsigned short* __restrict__ vT) {
  __shared__ unsigned short tile[64][72];
  const int t0 = blockIdx.x * 64;
  const int bh = blockIdx.y;
  const int b = bh >> 4;
  const int srow = threadIdx.x >> 3;       // 0..31
  const int sc8 = (threadIdx.x & 7) * 8;
#pragma unroll
  for (int it = 0; it < 2; ++it) {
    int r = srow + it * 32;
    *(uint4*)&tile[r][sc8] =
        *(const uint4*)(vP + (size_t)(b * T_ + t0 + r) * 1024 + (bh & 15) * 64 + sc8);
  }
  __syncthreads();
#pragma unroll
  for (int it = 0; it < 2; ++it) {
    int dd = srow + it * 32;
    union { unsigned short u[8]; uint4 v; } o;
#pragma unroll
    for (int j = 0; j < 8; ++j) o.u[j] = tile[sc8 + j][dd];
    *(uint4*)(vT + ((size_t)bh * 64 + dd) * 2048 + t0 + sc8) = o.v;
  }
}

// ---------------------------------------------------------------------------
// qkv GEMM v12: 256x256 tile, BK=64, 8 waves (2Mx4N), 512 threads.
// Counted-vmcnt deep prefetch (T4) with RAW s_barrier (avoids __syncthreads'
// forced vmcnt(0) drain -- the documented m97 ~540TF ceiling mechanism).
// Schedule per K-tile t (buf = t&1):
//   [64 MFMA from buf]                      (no intra-tile barriers)
//   s_barrier                                -- all waves done reading buf
//   STAGE(t+2 -> buf)                        -- 8 gl_lds16/wave, issue only
//   s_waitcnt vmcnt(8)                       -- waits t+1's (older) 8 loads,
//                                               never the fresh prefetch
//   s_barrier                                -- t+1 visible to ALL waves
// Hazards proven: stage is issued post-barrier (no write-before-read);
// vmcnt(8)+barrier makes every wave's t+1 loads globally visible.
// Swizzle byte-identical to the verified 128^2 kernel (0 conflicts in PMC):
// stage global chunk j=(lane&7)^(r&7), frag read chunk (g+kk*4)^(row&7).
// Epilogue: RoPE fused (HW trig, v10-verified, bitwise-identical math) ->
// 128KB LDS (staging bufs, dead after loop) -> 16x uint4 coalesced stores.
// ---------------------------------------------------------------------------
__global__ __launch_bounds__(512, 2) void gemm_qkv_256(
    const unsigned short* __restrict__ A,    // xb  [4096][1024]
    const unsigned short* __restrict__ BT,   // waT [3072][1024]
    const float* __restrict__ bias,
    unsigned short* __restrict__ qP, unsigned short* __restrict__ kP,
    unsigned short* __restrict__ vP) {
  __shared__ unsigned short L[65536];        // 128 KB
  unsigned short* As = L;                    // [2][256*64]
  unsigned short* Bs = L + 32768;            // [2][256*64]

  const int tid = threadIdx.x;
  const int wid = tid >> 6, lane = tid & 63;
  const int lo = lane & 15, g = lane >> 4;
  const int wr = wid >> 2, wc = wid & 3;     // wave grid 2M x 4N
  const int m0 = blockIdx.y * 256, n0 = blockIdx.x * 256;
  const int lr8 = lane >> 3;
  const int NT = 16;                         // K/64

  const f32x4 zero4 = {0.f, 0.f, 0.f, 0.f};
  f32x4 acc[8][4];
#pragma unroll
  for (int i = 0; i < 8; ++i)
#pragma unroll
    for (int j = 0; j < 4; ++j) acc[i][j] = zero4;

#define STAGE_QKV(t)                                                          \
  do {                                                                        \
    const int buf_ = ((t) & 1) ? 16384 : 0;                                   \
    const int k0_ = (t) * 64;                                                 \
    _Pragma("unroll")                                                         \
    for (int it = 0; it < 4; ++it) {                                          \
      const int br = wid * 32 + it * 8;                                       \
      const int r = br + lr8;                                                 \
      const int j = (lane & 7) ^ (r & 7);                                     \
      gl_lds16(A + (size_t)(m0 + r) * 1024 + k0_ + j * 8, &As[buf_ + br * 64]);\
    }                                                                         \
    _Pragma("unroll")                                                         \
    for (int it = 0; it < 4; ++it) {                                          \
      const int br = wid * 32 + it * 8;                                       \
      const int r = br + lr8;                                                 \
      const int j = (lane & 7) ^ (r & 7);                                     \
      gl_lds16(BT + (size_t)(n0 + r) * 1024 + k0_ + j * 8, &Bs[buf_ + br * 64]);\
    }                                                                         \
  } while (0)

  STAGE_QKV(0);
  STAGE_QKV(1);
  asm volatile("s_waitcnt vmcnt(8)" ::: "memory");   // tile 0 landed
  __builtin_amdgcn_s_barrier();

  for (int t = 0; t < NT; ++t) {
    const int buf = (t & 1) ? 16384 : 0;
#pragma unroll
    for (int kk = 0; kk < 2; ++kk) {
      bf16x8 af[8], bfr[4];
#pragma unroll
      for (int i = 0; i < 8; ++i) {
        const int ra = wr * 128 + i * 16 + lo;
        af[i] = *(const bf16x8*)&As[buf + ra * 64 + ((g + kk * 4) ^ (ra & 7)) * 8];
      }
#pragma unroll
      for (int j = 0; j < 4; ++j) {
        const int rb = wc * 64 + j * 16 + lo;
        bfr[j] = *(const bf16x8*)&Bs[buf + rb * 64 + ((g + kk * 4) ^ (rb & 7)) * 8];
      }
#pragma unroll
      for (int i = 0; i < 8; ++i)
#pragma unroll
        for (int j = 0; j < 4; ++j)
          acc[i][j] = __builtin_amdgcn_mfma_f32_16x16x32_bf16(af[i], bfr[j],
                                                              acc[i][j], 0, 0, 0);
    }
    __builtin_amdgcn_s_barrier();            // all reads of buf done
    if (t + 2 < NT) {
      STAGE_QKV(t + 2);
      asm volatile("s_waitcnt vmcnt(8)" ::: "memory");  // t+1 landed
      __builtin_amdgcn_s_barrier();
    } else if (t + 1 < NT) {
      asm volatile("s_waitcnt vmcnt(0)" ::: "memory");  // t+1 landed (nothing newer)
      __builtin_amdgcn_s_barrier();
    }
  }
#undef STAGE_QKV

  // ---- epilogue: values -> L (S[256][256] bf16), RoPE fused for q/k
  float bv[4];
#pragma unroll
  for (int j = 0; j < 4; ++j) bv[j] = bias[n0 + wc * 64 + j * 16 + lo];

  const int pl = n0 >> 10;                   // 0=q 1=k 2=v (256-tile never straddles)
  unsigned short* S = L;
  if (pl == 2) {
#pragma unroll
    for (int i = 0; i < 8; ++i)
#pragma unroll
      for (int r = 0; r < 4; ++r) {
        const int row = wr * 128 + i * 16 + g * 4 + r;
#pragma unroll
        for (int j = 0; j < 4; ++j)
          S[row * 256 + wc * 64 + j * 16 + lo] = f2bf(acc[i][j][r] + bv[j]);
      }
  } else {
    const float scale = (pl == 0) ? 0.125f : 1.0f;
    const float invA = exp2f((float)(-2 * lo) * (13.287712379549449f / 64.0f)) *
                       0.15915494309189535f;
    const float invB = exp2f((float)(-2 * (lo + 16)) * (13.287712379549449f / 64.0f)) *
                       0.15915494309189535f;
    const int c0 = wc * 64 + lo;
#pragma unroll
    for (int i = 0; i < 8; ++i)
#pragma unroll
      for (int r = 0; r < 4; ++r) {
        const int row = wr * 128 + i * 16 + g * 4 + r;
        const float t = (float)((m0 + row) & (T_ - 1));
        float ra = t * invA; ra -= floorf(ra);      // [0,1) revolutions
        float rb = t * invB; rb -= floorf(rb);
        const float sA = __builtin_amdgcn_sinf(ra);
        const float cA = __builtin_amdgcn_cosf(ra);
        const float sB = __builtin_amdgcn_sinf(rb);
        const float cB = __builtin_amdgcn_cosf(rb);
        const float q1A = acc[i][0][r] + bv[0];
        const float q2A = acc[i][2][r] + bv[2];
        const float q1B = acc[i][1][r] + bv[1];
        const float q2B = acc[i][3][r] + bv[3];
        S[row * 256 + c0]      = f2bf((q1A * cA - q2A * sA) * scale);
        S[row * 256 + c0 + 32] = f2bf((q2A * cA + q1A * sA) * scale);
        S[row * 256 + c0 + 16] = f2bf((q1B * cB - q2B * sB) * scale);
        S[row * 256 + c0 + 48] = f2bf((q2B * cB + q1B * sB) * scale);
      }
  }
  __builtin_amdgcn_s_barrier();
  // ---- vectorized store: 16x uint4/thread, coalesced
  unsigned short* P = (pl == 0) ? qP : (pl == 1) ? kP : vP;
  const int pcol0 = n0 & 1023;
#pragma unroll
  for (int it2 = 0; it2 < 16; ++it2) {
    const int p = it2 * 512 + tid;           // uint4 index 0..8191
    const int lrow = p >> 5;                 // 256 rows x 32 uint4
    const int lcol = (p & 31) * 8;
    uint4 v4 = *(const uint4*)&S[lrow * 256 + lcol];
    *(uint4*)(P + (size_t)(m0 + lrow) * 1024 + pcol0 + lcol) = v4;
  }
}

// ---------------------------------------------------------------------------
// proj GEMM (fp32 out): verified 128^2 m97-structure kernel, unchanged.
// ---------------------------------------------------------------------------
__global__ __launch_bounds__(256) void mfma_gemm_f32(
    const unsigned short* __restrict__ A,
    const unsigned short* __restrict__ BT,
    const float* __restrict__ bias,
    float* __restrict__ Fout,
    int N, int K) {
  __shared__ unsigned short S[128 * 128];   // loop: As|Bs; epilogue: float view
  unsigned short* As = S;
  unsigned short* Bs = S + 128 * 64;

  const int tid = threadIdx.x;
  const int w = tid >> 6, lane = tid & 63;
  const int lo = lane & 15, g = lane >> 4;
  const int wm = (w >> 1) * 64, wn = (w & 1) * 64;
  const int m0 = blockIdx.y * 128, n0 = blockIdx.x * 128;

  const int lr8 = lane >> 3;

  const f32x4 zero4 = {0.f, 0.f, 0.f, 0.f};
  f32x4 acc[4][4] = {{zero4, zero4, zero4, zero4}, {zero4, zero4, zero4, zero4},
                     {zero4, zero4, zero4, zero4}, {zero4, zero4, zero4, zero4}};

  for (int k0 = 0; k0 < K; k0 += 64) {
    __syncthreads();
#pragma unroll
    for (int it = 0; it < 4; ++it) {
      const int base_row = w * 32 + it * 8;
      const int r = base_row + lr8;
      const int j = (lane & 7) ^ (r & 7);
      gl_lds16(A + (size_t)(m0 + r) * K + k0 + j * 8, &As[base_row * 64]);
      gl_lds16(BT + (size_t)(n0 + r) * K + k0 + j * 8, &Bs[base_row * 64]);
    }
    __syncthreads();

#pragma unroll
    for (int kk = 0; kk < 2; ++kk) {
      bf16x8 af[4], bfr[4];
#pragma unroll
      for (int i = 0; i < 4; ++i) {
        int ra = wm + i * 16 + lo;
        int rb = wn + i * 16 + lo;
        af[i]  = *(const bf16x8*)&As[ra * 64 + ((g + kk * 4) ^ (ra & 7)) * 8];
        bfr[i] = *(const bf16x8*)&Bs[rb * 64 + ((g + kk * 4) ^ (rb & 7)) * 8];
      }
#pragma unroll
      for (int i = 0; i < 4; ++i)
#pragma unroll
        for (int j = 0; j < 4; ++j)
          acc[i][j] = __builtin_amdgcn_mfma_f32_16x16x32_bf16(af[i], bfr[j],
                                                              acc[i][j], 0, 0, 0);
    }
  }

  float bv[4];
#pragma unroll
  for (int j = 0; j < 4; ++j) bv[j] = bias[n0 + wn + j * 16 + lo];

  float* Sf = (float*)S;
#pragma unroll
  for (int hh = 0; hh < 2; ++hh) {
    __syncthreads();
    if ((w >> 1) == hh) {
#pragma unroll
      for (int i = 0; i < 4; ++i)
#pragma unroll
        for (int r = 0; r < 4; ++r) {
          const int lrow = i * 16 + g * 4 + r;
#pragma unroll
          for (int j = 0; j < 4; ++j)
            Sf[lrow * 128 + wn + j * 16 + lo] = acc[i][j][r] + bv[j];
        }
    }
    __syncthreads();
#pragma unroll
    for (int it2 = 0; it2 < 8; ++it2) {
      const int p = it2 * 256 + tid;
      const int lrow = p >> 5;
      const int lcol = (p & 31) * 4;
      float4 v4 = *(const float4*)&Sf[lrow * 128 + lcol];
      *(float4*)(Fout + (size_t)(m0 + hh * 64 + lrow) * N + n0 + lcol) = v4;
    }
  }
}

// ---------------------------------------------------------------------------
// flash (verified 46.4us): paired tiles, swapped QK^T, b64 P-write, scalar
// lsum, setprio, double-barrier staging + reg prefetch, XCD-chunked grid.
// ---------------------------------------------------------------------------
__global__ __launch_bounds__(256) void flash_mfma6(
    unsigned short* __restrict__ qP,
    const unsigned short* __restrict__ kP,
    const unsigned short* __restrict__ vT) {
  const int cid = blockIdx.x;            // 0..511
  const int xcd = cid & 7;
  const int k6 = cid >> 3;               // 0..63
  const int bh = xcd * 4 + (k6 >> 4);    // 4 bh per XCD
  const int bx = k6 & 15;                // 0..15
  const int b = bh >> 4, h = bh & 15;
  const int tid = threadIdx.x;
  const int w = tid >> 6, lane = tid & 63;
  const int lo = lane & 15, g = lane >> 4;

  __shared__ unsigned short Ks[64][72];   // [key][d]
  __shared__ unsigned short VTs[64][72];  // [d][key]
  __shared__ unsigned short Ps[64][72];   // [q][key]

  const int srow = tid >> 3;        // 0..31
  const int sc8 = (tid & 7) * 8;
  const f32x4 zero4 = {0.f, 0.f, 0.f, 0.f};

#pragma unroll
  for (int half = 0; half < 2; ++half) {
    const int qt = half ? (31 - bx) : bx;
    const int rowq0 = b * T_ + qt * 64;

    const unsigned short* qrow = qP + (size_t)(rowq0 + w * 16 + lo) * 1024 + h * 64;
    bf16x8 aq0 = *(const bf16x8*)(qrow + g * 8);
    bf16x8 aq1 = *(const bf16x8*)(qrow + 32 + g * 8);

    f32x4 oacc[4] = {zero4, zero4, zero4, zero4};
    float lsum = 0.f;

    uint4 kreg0, kreg1, vreg0, vreg1;
    {
      const size_t kb = (size_t)(b * T_ + srow) * 1024 + h * 64 + sc8;
      kreg0 = *(const uint4*)(kP + kb);
      kreg1 = *(const uint4*)(kP + kb + (size_t)32 * 1024);
      const size_t vb = ((size_t)bh * 64 + srow) * 2048 + sc8;
      vreg0 = *(const uint4*)(vT + vb);
      vreg1 = *(const uint4*)(vT + vb + (size_t)32 * 2048);
    }

    for (int kt = 0; kt <= qt; ++kt) {
      __syncthreads();
      *(uint4*)&Ks[srow][sc8]       = kreg0;
      *(uint4*)&Ks[srow + 32][sc8]  = kreg1;
      *(uint4*)&VTs[srow][sc8]      = vreg0;
      *(uint4*)&VTs[srow + 32][sc8] = vreg1;
      __syncthreads();
      if (kt < qt) {
        const size_t kb = (size_t)(b * T_ + (kt + 1) * 64 + srow) * 1024 + h * 64 + sc8;
        kreg0 = *(const uint4*)(kP + kb);
        kreg1 = *(const uint4*)(kP + kb + (size_t)32 * 1024);
        const size_t vb = ((size_t)bh * 64 + srow) * 2048 + (kt + 1) * 64 + sc8;
        vreg0 = *(const uint4*)(vT + vb);
        vreg1 = *(const uint4*)(vT + vb + (size_t)32 * 2048);
      }

      f32x4 sacc[4] = {zero4, zero4, zero4, zero4};
      __builtin_amdgcn_s_setprio(1);
#pragma unroll
      for (int ct = 0; ct < 4; ++ct) {
        bf16x8 bk0 = *(const bf16x8*)&Ks[ct * 16 + lo][g * 8];
        bf16x8 bk1 = *(const bf16x8*)&Ks[ct * 16 + lo][32 + g * 8];
        sacc[ct] = __builtin_amdgcn_mfma_f32_16x16x32_bf16(bk0, aq0, sacc[ct], 0, 0, 0);
        sacc[ct] = __builtin_amdgcn_mfma_f32_16x16x32_bf16(bk1, aq1, sacc[ct], 0, 0, 0);
      }
      __builtin_amdgcn_s_setprio(0);

      if (kt == qt) {
#pragma unroll
        for (int ct = 0; ct < 4; ++ct)
#pragma unroll
          for (int r = 0; r < 4; ++r)
            if (ct * 16 + g * 4 + r > w * 16 + lo) sacc[ct][r] = -1e30f;
      }

#pragma unroll
      for (int ct = 0; ct < 4; ++ct) {
        float p0 = __expf(sacc[ct][0]);
        float p1 = __expf(sacc[ct][1]);
        float p2 = __expf(sacc[ct][2]);
        float p3 = __expf(sacc[ct][3]);
        lsum += (p0 + p1) + (p2 + p3);
        unsigned int u0 = (unsigned int)f2bf(p0) | ((unsigned int)f2bf(p1) << 16);
        unsigned int u1 = (unsigned int)f2bf(p2) | ((unsigned int)f2bf(p3) << 16);
        uint2 pw; pw.x = u0; pw.y = u1;
        *(uint2*)&Ps[w * 16 + lo][ct * 16 + g * 4] = pw;
      }

      bf16x8 ap0 = *(const bf16x8*)&Ps[w * 16 + lo][g * 8];
      bf16x8 ap1 = *(const bf16x8*)&Ps[w * 16 + lo][32 + g * 8];
      __builtin_amdgcn_s_setprio(1);
#pragma unroll
      for (int c2 = 0; c2 < 4; ++c2) {
        bf16x8 bv0 = *(const bf16x8*)&VTs[c2 * 16 + lo][g * 8];
        bf16x8 bv1 = *(const bf16x8*)&VTs[c2 * 16 + lo][32 + g * 8];
        oacc[c2] = __builtin_amdgcn_mfma_f32_16x16x32_bf16(ap0, bv0, oacc[c2], 0, 0, 0);
        oacc[c2] = __builtin_amdgcn_mfma_f32_16x16x32_bf16(ap1, bv1, oacc[c2], 0, 0, 0);
      }
      __builtin_amdgcn_s_setprio(0);
    }

    lsum += __shfl_xor(lsum, 16);
    lsum += __shfl_xor(lsum, 32);

#pragma unroll
    for (int r = 0; r < 4; ++r) {
      float inv_r = 1.0f / __shfl(lsum, g * 4 + r);
      unsigned short* dst = qP + (size_t)(rowq0 + w * 16 + g * 4 + r) * 1024 + h * 64 + lo;
#pragma unroll
      for (int c2 = 0; c2 < 4; ++c2)
        dst[c2 * 16] = f2bf(oacc[c2][r] * inv_r);
    }
  }
}

// ---------------------------------------------------------------------------
extern "C" void kernel_launch(void* const* d_in, const int* in_sizes, int n_in,
                              void* d_out, int out_size, void* d_ws, size_t ws_size,
                              hipStream_t stream) {
  const float *x = nullptr, *w_attn = nullptr, *b_attn = nullptr,
              *w_proj = nullptr, *b_proj = nullptr;
  for (int i = 0; i < n_in; ++i) {
    switch (in_sizes[i]) {
      case B_ * T_ * C_:  x      = (const float*)d_in[i]; break;
      case C_ * 3 * C_:   w_attn = (const float*)d_in[i]; break;
      case 3 * C_:        b_attn = (const float*)d_in[i]; break;
      case C_ * C_:       w_proj = (const float*)d_in[i]; break;
      case C_:            b_proj = (const float*)d_in[i]; break;
      default: break;
    }
  }
  float* out = (float*)d_out;
  const int nblk = (out_size + 255) / 256;

  if (!x || !w_attn || !b_attn || !w_proj || !b_proj) {
    fill_kernel_f32<<<nblk, 256, 0, stream>>>(out, out_size, 100.0f);  // SENTINEL
    return;
  }
  // ws >= 48 MB proven (rounds 10/11 fast path). Sentinel otherwise.
  if (ws_size < (size_t)48 * 1024 * 1024) {
    fill_kernel_f32<<<nblk, 256, 0, stream>>>(out, out_size, 50.0f);   // SENTINEL
    return;
  }

  // layout: q|k|v planes (24 MB) | vT (8) | xb (8) | waT (6) | wpT (2) = 48 MB
  unsigned short* qP  = (unsigned short*)d_ws;
  unsigned short* kP  = qP + (size_t)(B_ * T_) * 1024;
  unsigned short* vP  = kP + (size_t)(B_ * T_) * 1024;
  unsigned short* vT  = vP + (size_t)(B_ * T_) * 1024;
  unsigned short* xb  = vT + (size_t)(B_ * T_) * 1024;
  unsigned short* waT = xb + (size_t)(B_ * T_) * C_;
  unsigned short* wpT = waT + (size_t)C_ * 3 * C_;

  // 0) fused prep: weight transposes + x conversion
  prep_kernel<<<dim3(96, 32, 3), 256, 0, stream>>>(w_attn, w_proj, x, waT, wpT, xb);
  // 1) qkv = xb @ w_attn + b_attn: 256^2 8-wave counted-vmcnt GEMM, RoPE fused
  gemm_qkv_256<<<dim3((3 * C_) / 256, (B_ * T_) / 256), 512, 0, stream>>>(
      xb, waT, b_attn, qP, kP, vP);
  // 2) V transpose for conflict-free flash staging
  v_transpose<<<dim3(T_ / 64, B_ * H_), 256, 0, stream>>>(vP, vT);
  // 3) causal flash attention (XCD-chunked grid)
  flash_mfma6<<<dim3(512), 256, 0, stream>>>(qP, kP, vT);
  // 4) out = y @ w_proj + b_proj (fp32 out, vectorized epilogue)
  mfma_gemm_f32<<<dim3(C_ / 128, (B_ * T_) / 128), 256, 0, stream>>>(
      qP, wpT, b_proj, out, C_, C_);
}

// Round 10
// 183.590 us; speedup vs baseline: 1.0284x; 1.0284x over previous
//
#include <hip/hip_runtime.h>
#include <hip/hip_bf16.h>

#define B_ 2
#define T_ 2048
#define C_ 1024
#define H_ 16
#define D_ 64

typedef __attribute__((ext_vector_type(8))) short bf16x8;
typedef __attribute__((ext_vector_type(4))) float f32x4;

static __device__ __forceinline__ float bf2f(unsigned short u) {
  union { unsigned int i; float f; } c;
  c.i = ((unsigned int)u) << 16;
  return c.f;
}
static __device__ __forceinline__ unsigned short f2bf(float f) {
  union { float f; unsigned int i; } c;
  c.f = f;
  unsigned int x = c.i;
  return (unsigned short)((x + 0x7fffu + ((x >> 16) & 1u)) >> 16);  // RNE
}

// async global->LDS, 16B per lane; LDS dest = (wave-uniform base) + lane*16
static __device__ __forceinline__ void gl_lds16(const void* g, void* s) {
  __builtin_amdgcn_global_load_lds(
      (const __attribute__((address_space(1))) void*)g,
      (__attribute__((address_space(3))) void*)s, 16, 0, 0);
}

// ---------------------------------------------------------------------------
__global__ __launch_bounds__(256) void fill_kernel_f32(float* __restrict__ out,
                                                       int n, float v) {
  int i = blockIdx.x * 256 + threadIdx.x;
  if (i < n) out[i] = v;
}

// ---------------------------------------------------------------------------
// Fused prep:
//   z=0: w_attn [1024][3072] -> waT [3072][1024] bf16   (96x32 tiles)
//   z=1: w_proj [1024][1024] -> wpT [1024][1024] bf16
//   z=2: x fp32 -> xb bf16, 8 elems/thread
// ---------------------------------------------------------------------------
__global__ __launch_bounds__(256) void prep_kernel(
    const float* __restrict__ w_attn, const float* __restrict__ w_proj,
    const float* __restrict__ x,
    unsigned short* __restrict__ waT, unsigned short* __restrict__ wpT,
    unsigned short* __restrict__ xb) {
  __shared__ float tile[32][33];
  const int z = blockIdx.z;
  if (z == 2) {
    const int id = blockIdx.y * 96 + blockIdx.x;
    if (id >= 2048) return;
    int i = (id * 256 + threadIdx.x) * 8;
    float4 f0 = *(const float4*)(x + i);
    float4 f1 = *(const float4*)(x + i + 4);
    union { unsigned short u[8]; uint4 v; } p;
    p.u[0] = f2bf(f0.x); p.u[1] = f2bf(f0.y); p.u[2] = f2bf(f0.z); p.u[3] = f2bf(f0.w);
    p.u[4] = f2bf(f1.x); p.u[5] = f2bf(f1.y); p.u[6] = f2bf(f1.z); p.u[7] = f2bf(f1.w);
    *(uint4*)(xb + i) = p.v;
    return;
  }
  const float* W;
  unsigned short* WT;
  int Kd, Nd;
  if (z == 0) { W = w_attn; WT = waT; Kd = 1024; Nd = 3072; }
  else {
    if (blockIdx.x >= 32) return;
    W = w_proj; WT = wpT; Kd = 1024; Nd = 1024;
  }
  const int n0 = blockIdx.x * 32, k0 = blockIdx.y * 32;
  const int tx = threadIdx.x & 31, ty = threadIdx.x >> 5;  // ty 0..7
#pragma unroll
  for (int i = 0; i < 4; ++i)
    tile[ty + i * 8][tx] = W[(size_t)(k0 + ty + i * 8) * Nd + n0 + tx];
  __syncthreads();
#pragma unroll
  for (int i = 0; i < 4; ++i)
    WT[(size_t)(n0 + ty + i * 8) * Kd + k0 + tx] = f2bf(tile[tx][ty + i * 8]);
}

// ---------------------------------------------------------------------------
// MFMA GEMM: C = A(bf16)[M,K] @ BT(bf16)[N,K]^T + bias.
// 128x128 tile, BK=64, 4 waves, m97 staging (verified).
// OUT_PLANES=1:
//   q/k planes: RoPE fused (HW trig, v10-verified) -> LDS -> 8x uint4 stores.
//   v plane (pl==2): DIRECT TRANSPOSED store to vT -- thread's acc[i][j][0..3]
//     are 4 consecutive t at one col=h*64+d, i.e. one uint2 of
//     vT[(b*1024+col)*2048 + t]. Per wave+col the (i,g) iterations tile a
//     full 128B t-run, so L2 assembles complete lines. Replaces the separate
//     v_transpose kernel (+launch) and the whole vP round-trip.
// OUT_PLANES=0: fp32 out via two 64-row LDS passes, 8x float4 stores.
// ---------------------------------------------------------------------------
template <int OUT_PLANES>
__global__ __launch_bounds__(256) void mfma_gemm(
    const unsigned short* __restrict__ A,
    const unsigned short* __restrict__ BT,
    const float* __restrict__ bias,
    unsigned short* __restrict__ qP, unsigned short* __restrict__ kP,
    unsigned short* __restrict__ vT, float* __restrict__ Fout,
    int N, int K) {
  __shared__ unsigned short S[128 * 128];   // loop: As|Bs; epilogue: staging
  unsigned short* As = S;
  unsigned short* Bs = S + 128 * 64;

  const int tid = threadIdx.x;
  const int w = tid >> 6, lane = tid & 63;
  const int lo = lane & 15, g = lane >> 4;
  const int wm = (w >> 1) * 64, wn = (w & 1) * 64;
  const int m0 = blockIdx.y * 128, n0 = blockIdx.x * 128;

  const int lr8 = lane >> 3;           // row within the 8-row instr span

  const f32x4 zero4 = {0.f, 0.f, 0.f, 0.f};
  f32x4 acc[4][4] = {{zero4, zero4, zero4, zero4}, {zero4, zero4, zero4, zero4},
                     {zero4, zero4, zero4, zero4}, {zero4, zero4, zero4, zero4}};

  for (int k0 = 0; k0 < K; k0 += 64) {
    __syncthreads();  // previous iteration's frag readers done
#pragma unroll
    for (int it = 0; it < 4; ++it) {
      const int base_row = w * 32 + it * 8;       // wave-uniform
      const int r = base_row + lr8;               // this lane's row
      const int j = (lane & 7) ^ (r & 7);         // global chunk for LDS chunk lane&7
      gl_lds16(A + (size_t)(m0 + r) * K + k0 + j * 8, &As[base_row * 64]);
      gl_lds16(BT + (size_t)(n0 + r) * K + k0 + j * 8, &Bs[base_row * 64]);
    }
    __syncthreads();  // drains vmcnt -> staging visible

#pragma unroll
    for (int kk = 0; kk < 2; ++kk) {
      bf16x8 af[4], bfr[4];
#pragma unroll
      for (int i = 0; i < 4; ++i) {
        int ra = wm + i * 16 + lo;
        int rb = wn + i * 16 + lo;
        af[i]  = *(const bf16x8*)&As[ra * 64 + ((g + kk * 4) ^ (ra & 7)) * 8];
        bfr[i] = *(const bf16x8*)&Bs[rb * 64 + ((g + kk * 4) ^ (rb & 7)) * 8];
      }
#pragma unroll
      for (int i = 0; i < 4; ++i)
#pragma unroll
        for (int j = 0; j < 4; ++j)
          acc[i][j] = __builtin_amdgcn_mfma_f32_16x16x32_bf16(af[i], bfr[j],
                                                              acc[i][j], 0, 0, 0);
    }
  }

  float bv[4];
#pragma unroll
  for (int j = 0; j < 4; ++j) bv[j] = bias[n0 + wn + j * 16 + lo];

  if (OUT_PLANES) {
    const int pl = n0 >> 10;
    if (pl == 2) {
      // ---- v plane: direct transposed store to vT (no LDS, no barriers;
      //      pl is block-uniform so barrier counts stay uniform)
      const int b = m0 >> 11;                  // uniform per block (2048%128==0)
      const int t0base = m0 & 2047;
      const int colbase = (n0 & 1023) + wn + lo;   // + j*16 -> col = h*64+d
#pragma unroll
      for (int i = 0; i < 4; ++i) {
        const int tt = t0base + wm + i * 16 + g * 4;   // + r (consecutive)
#pragma unroll
        for (int j = 0; j < 4; ++j) {
          const int col = colbase + j * 16;
          unsigned int u0 = (unsigned int)f2bf(acc[i][j][0] + bv[j]) |
                            ((unsigned int)f2bf(acc[i][j][1] + bv[j]) << 16);
          unsigned int u1 = (unsigned int)f2bf(acc[i][j][2] + bv[j]) |
                            ((unsigned int)f2bf(acc[i][j][3] + bv[j]) << 16);
          uint2 pw; pw.x = u0; pw.y = u1;
          *(uint2*)(vT + ((size_t)(b * 1024 + col)) * 2048 + tt) = pw;
        }
      }
    } else {
      __syncthreads();  // all frag readers done; S reusable
      // ---- q/k planes: fused RoPE (HW trig in revolutions; v10-verified)
      const float scale = (pl == 0) ? 0.125f : 1.0f;
      const float invA = exp2f((float)(-2 * lo) * (13.287712379549449f / 64.0f)) *
                         0.15915494309189535f;
      const float invB = exp2f((float)(-2 * (lo + 16)) * (13.287712379549449f / 64.0f)) *
                         0.15915494309189535f;
      const int c0 = wn + lo;
#pragma unroll
      for (int i = 0; i < 4; ++i)
#pragma unroll
        for (int r = 0; r < 4; ++r) {
          const int row = wm + i * 16 + g * 4 + r;
          const float t = (float)((m0 + row) & (T_ - 1));
          float ra = t * invA; ra -= floorf(ra);    // [0,1) revolutions
          float rb = t * invB; rb -= floorf(rb);
          const float sA = __builtin_amdgcn_sinf(ra);
          const float cA = __builtin_amdgcn_cosf(ra);
          const float sB = __builtin_amdgcn_sinf(rb);
          const float cB = __builtin_amdgcn_cosf(rb);
          const float q1A = acc[i][0][r] + bv[0];
          const float q2A = acc[i][2][r] + bv[2];
          const float q1B = acc[i][1][r] + bv[1];
          const float q2B = acc[i][3][r] + bv[3];
          S[row * 128 + c0]      = f2bf((q1A * cA - q2A * sA) * scale);
          S[row * 128 + c0 + 32] = f2bf((q2A * cA + q1A * sA) * scale);
          S[row * 128 + c0 + 16] = f2bf((q1B * cB - q2B * sB) * scale);
          S[row * 128 + c0 + 48] = f2bf((q2B * cB + q1B * sB) * scale);
        }
      __syncthreads();
      // ---- vectorized store: 8x uint4/thread, coalesced
      unsigned short* P = (pl == 0) ? qP : kP;
      const int pcol0 = n0 & 1023;
#pragma unroll
      for (int it2 = 0; it2 < 8; ++it2) {
        const int p = it2 * 256 + tid;          // uint4 index 0..2047
        const int lrow = p >> 4;                // 128 rows x 16 uint4
        const int lcol = (p & 15) * 8;
        uint4 v4 = *(const uint4*)&S[lrow * 128 + lcol];
        *(uint4*)(P + (size_t)(m0 + lrow) * 1024 + pcol0 + lcol) = v4;
      }
    }
  } else {
    // ---- fp32 out via two 64-row LDS passes (S as float[64][128])
    float* Sf = (float*)S;
#pragma unroll
    for (int hh = 0; hh < 2; ++hh) {
      __syncthreads();
      if ((w >> 1) == hh) {
#pragma unroll
        for (int i = 0; i < 4; ++i)
#pragma unroll
          for (int r = 0; r < 4; ++r) {
            const int lrow = i * 16 + g * 4 + r;
#pragma unroll
            for (int j = 0; j < 4; ++j)
              Sf[lrow * 128 + wn + j * 16 + lo] = acc[i][j][r] + bv[j];
          }
      }
      __syncthreads();
#pragma unroll
      for (int it2 = 0; it2 < 8; ++it2) {
        const int p = it2 * 256 + tid;        // float4 index 0..2047
        const int lrow = p >> 5;              // 64 rows x 32 float4
        const int lcol = (p & 31) * 4;
        float4 v4 = *(const float4*)&Sf[lrow * 128 + lcol];
        *(float4*)(Fout + (size_t)(m0 + hh * 64 + lrow) * N + n0 + lcol) = v4;
      }
    }
  }
}

// ---------------------------------------------------------------------------
// flash (verified 46.4us): paired tiles, swapped QK^T, b64 P-write, scalar
// lsum, setprio, double-barrier staging + reg prefetch, XCD-chunked grid.
// ---------------------------------------------------------------------------
__global__ __launch_bounds__(256) void flash_mfma6(
    unsigned short* __restrict__ qP,
    const unsigned short* __restrict__ kP,
    const unsigned short* __restrict__ vT) {
  const int cid = blockIdx.x;            // 0..511
  const int xcd = cid & 7;
  const int k6 = cid >> 3;               // 0..63
  const int bh = xcd * 4 + (k6 >> 4);    // 4 bh per XCD
  const int bx = k6 & 15;                // 0..15
  const int b = bh >> 4, h = bh & 15;
  const int tid = threadIdx.x;
  const int w = tid >> 6, lane = tid & 63;
  const int lo = lane & 15, g = lane >> 4;

  __shared__ unsigned short Ks[64][72];   // [key][d]
  __shared__ unsigned short VTs[64][72];  // [d][key]
  __shared__ unsigned short Ps[64][72];   // [q][key]

  const int srow = tid >> 3;        // 0..31
  const int sc8 = (tid & 7) * 8;
  const f32x4 zero4 = {0.f, 0.f, 0.f, 0.f};

#pragma unroll
  for (int half = 0; half < 2; ++half) {
    const int qt = half ? (31 - bx) : bx;
    const int rowq0 = b * T_ + qt * 64;

    const unsigned short* qrow = qP + (size_t)(rowq0 + w * 16 + lo) * 1024 + h * 64;
    bf16x8 aq0 = *(const bf16x8*)(qrow + g * 8);
    bf16x8 aq1 = *(const bf16x8*)(qrow + 32 + g * 8);

    f32x4 oacc[4] = {zero4, zero4, zero4, zero4};
    float lsum = 0.f;

    uint4 kreg0, kreg1, vreg0, vreg1;
    {
      const size_t kb = (size_t)(b * T_ + srow) * 1024 + h * 64 + sc8;
      kreg0 = *(const uint4*)(kP + kb);
      kreg1 = *(const uint4*)(kP + kb + (size_t)32 * 1024);
      const size_t vb = ((size_t)bh * 64 + srow) * 2048 + sc8;
      vreg0 = *(const uint4*)(vT + vb);
      vreg1 = *(const uint4*)(vT + vb + (size_t)32 * 2048);
    }

    for (int kt = 0; kt <= qt; ++kt) {
      __syncthreads();
      *(uint4*)&Ks[srow][sc8]       = kreg0;
      *(uint4*)&Ks[srow + 32][sc8]  = kreg1;
      *(uint4*)&VTs[srow][sc8]      = vreg0;
      *(uint4*)&VTs[srow + 32][sc8] = vreg1;
      __syncthreads();
      if (kt < qt) {
        const size_t kb = (size_t)(b * T_ + (kt + 1) * 64 + srow) * 1024 + h * 64 + sc8;
        kreg0 = *(const uint4*)(kP + kb);
        kreg1 = *(const uint4*)(kP + kb + (size_t)32 * 1024);
        const size_t vb = ((size_t)bh * 64 + srow) * 2048 + (kt + 1) * 64 + sc8;
        vreg0 = *(const uint4*)(vT + vb);
        vreg1 = *(const uint4*)(vT + vb + (size_t)32 * 2048);
      }

      f32x4 sacc[4] = {zero4, zero4, zero4, zero4};
      __builtin_amdgcn_s_setprio(1);
#pragma unroll
      for (int ct = 0; ct < 4; ++ct) {
        bf16x8 bk0 = *(const bf16x8*)&Ks[ct * 16 + lo][g * 8];
        bf16x8 bk1 = *(const bf16x8*)&Ks[ct * 16 + lo][32 + g * 8];
        sacc[ct] = __builtin_amdgcn_mfma_f32_16x16x32_bf16(bk0, aq0, sacc[ct], 0, 0, 0);
        sacc[ct] = __builtin_amdgcn_mfma_f32_16x16x32_bf16(bk1, aq1, sacc[ct], 0, 0, 0);
      }
      __builtin_amdgcn_s_setprio(0);

      if (kt == qt) {
#pragma unroll
        for (int ct = 0; ct < 4; ++ct)
#pragma unroll
          for (int r = 0; r < 4; ++r)
            if (ct * 16 + g * 4 + r > w * 16 + lo) sacc[ct][r] = -1e30f;
      }

#pragma unroll
      for (int ct = 0; ct < 4; ++ct) {
        float p0 = __expf(sacc[ct][0]);
        float p1 = __expf(sacc[ct][1]);
        float p2 = __expf(sacc[ct][2]);
        float p3 = __expf(sacc[ct][3]);
        lsum += (p0 + p1) + (p2 + p3);
        unsigned int u0 = (unsigned int)f2bf(p0) | ((unsigned int)f2bf(p1) << 16);
        unsigned int u1 = (unsigned int)f2bf(p2) | ((unsigned int)f2bf(p3) << 16);
        uint2 pw; pw.x = u0; pw.y = u1;
        *(uint2*)&Ps[w * 16 + lo][ct * 16 + g * 4] = pw;
      }

      bf16x8 ap0 = *(const bf16x8*)&Ps[w * 16 + lo][g * 8];
      bf16x8 ap1 = *(const bf16x8*)&Ps[w * 16 + lo][32 + g * 8];
      __builtin_amdgcn_s_setprio(1);
#pragma unroll
      for (int c2 = 0; c2 < 4; ++c2) {
        bf16x8 bv0 = *(const bf16x8*)&VTs[c2 * 16 + lo][g * 8];
        bf16x8 bv1 = *(const bf16x8*)&VTs[c2 * 16 + lo][32 + g * 8];
        oacc[c2] = __builtin_amdgcn_mfma_f32_16x16x32_bf16(ap0, bv0, oacc[c2], 0, 0, 0);
        oacc[c2] = __builtin_amdgcn_mfma_f32_16x16x32_bf16(ap1, bv1, oacc[c2], 0, 0, 0);
      }
      __builtin_amdgcn_s_setprio(0);
    }

    lsum += __shfl_xor(lsum, 16);
    lsum += __shfl_xor(lsum, 32);

#pragma unroll
    for (int r = 0; r < 4; ++r) {
      float inv_r = 1.0f / __shfl(lsum, g * 4 + r);
      unsigned short* dst = qP + (size_t)(rowq0 + w * 16 + g * 4 + r) * 1024 + h * 64 + lo;
#pragma unroll
      for (int c2 = 0; c2 < 4; ++c2)
        dst[c2 * 16] = f2bf(oacc[c2][r] * inv_r);
    }
  }
}

// ---------------------------------------------------------------------------
extern "C" void kernel_launch(void* const* d_in, const int* in_sizes, int n_in,
                              void* d_out, int out_size, void* d_ws, size_t ws_size,
                              hipStream_t stream) {
  const float *x = nullptr, *w_attn = nullptr, *b_attn = nullptr,
              *w_proj = nullptr, *b_proj = nullptr;
  for (int i = 0; i < n_in; ++i) {
    switch (in_sizes[i]) {
      case B_ * T_ * C_:  x      = (const float*)d_in[i]; break;
      case C_ * 3 * C_:   w_attn = (const float*)d_in[i]; break;
      case 3 * C_:        b_attn = (const float*)d_in[i]; break;
      case C_ * C_:       w_proj = (const float*)d_in[i]; break;
      case C_:            b_proj = (const float*)d_in[i]; break;
      default: break;
    }
  }
  float* out = (float*)d_out;
  const int nblk = (out_size + 255) / 256;

  if (!x || !w_attn || !b_attn || !w_proj || !b_proj) {
    fill_kernel_f32<<<nblk, 256, 0, stream>>>(out, out_size, 100.0f);  // SENTINEL
    return;
  }
  // ws >= 48 MB proven (rounds 10/11 fast path). Sentinel otherwise.
  if (ws_size < (size_t)48 * 1024 * 1024) {
    fill_kernel_f32<<<nblk, 256, 0, stream>>>(out, out_size, 50.0f);   // SENTINEL
    return;
  }

  // layout: q|k planes (16 MB) | vP slot (8, unused) | vT (8) | xb (8) |
  //         waT (6) | wpT (2) = 48 MB
  unsigned short* qP  = (unsigned short*)d_ws;
  unsigned short* kP  = qP + (size_t)(B_ * T_) * 1024;
  unsigned short* vP  = kP + (size_t)(B_ * T_) * 1024;   // unused (kept for layout)
  unsigned short* vT  = vP + (size_t)(B_ * T_) * 1024;
  unsigned short* xb  = vT + (size_t)(B_ * T_) * 1024;
  unsigned short* waT = xb + (size_t)(B_ * T_) * C_;
  unsigned short* wpT = waT + (size_t)C_ * 3 * C_;
  (void)vP;

  // 0) fused prep: weight transposes + x conversion
  prep_kernel<<<dim3(96, 32, 3), 256, 0, stream>>>(w_attn, w_proj, x, waT, wpT, xb);
  // 1) qkv = xb @ w_attn + b_attn; RoPE fused (q/k), V transposed-stored to vT
  mfma_gemm<1><<<dim3((3 * C_) / 128, (B_ * T_) / 128), 256, 0, stream>>>(
      xb, waT, b_attn, qP, kP, vT, nullptr, 3 * C_, C_);
  // 2) causal flash attention (XCD-chunked grid)
  flash_mfma6<<<dim3(512), 256, 0, stream>>>(qP, kP, vT);
  // 3) out = y @ w_proj + b_proj (fp32 out, vectorized epilogue)
  mfma_gemm<0><<<dim3(C_ / 128, (B_ * T_) / 128), 256, 0, stream>>>(
      qP, wpT, b_proj, nullptr, nullptr, nullptr, out, C_, C_);
}

// Round 11
// 183.113 us; speedup vs baseline: 1.0311x; 1.0026x over previous
//
#include <hip/hip_runtime.h>
#include <hip/hip_bf16.h>

#define B_ 2
#define T_ 2048
#define C_ 1024
#define H_ 16
#define D_ 64

typedef __attribute__((ext_vector_type(8))) short bf16x8;
typedef __attribute__((ext_vector_type(4))) float f32x4;

static __device__ __forceinline__ float bf2f(unsigned short u) {
  union { unsigned int i; float f; } c;
  c.i = ((unsigned int)u) << 16;
  return c.f;
}
static __device__ __forceinline__ unsigned short f2bf(float f) {
  union { float f; unsigned int i; } c;
  c.f = f;
  unsigned int x = c.i;
  return (unsigned short)((x + 0x7fffu + ((x >> 16) & 1u)) >> 16);  // RNE
}

// async global->LDS, 16B per lane; LDS dest = (wave-uniform base) + lane*16
static __device__ __forceinline__ void gl_lds16(const void* g, void* s) {
  __builtin_amdgcn_global_load_lds(
      (const __attribute__((address_space(1))) void*)g,
      (__attribute__((address_space(3))) void*)s, 16, 0, 0);
}

// ---------------------------------------------------------------------------
__global__ __launch_bounds__(256) void fill_kernel_f32(float* __restrict__ out,
                                                       int n, float v) {
  int i = blockIdx.x * 256 + threadIdx.x;
  if (i < n) out[i] = v;
}

// ---------------------------------------------------------------------------
// Fused prep:
//   z=0: w_attn [1024][3072] -> waT [3072][1024] bf16   (96x32 tiles)
//   z=1: w_proj [1024][1024] -> wpT [1024][1024] bf16
//   z=2: x fp32 -> xb bf16, 8 elems/thread
// ---------------------------------------------------------------------------
__global__ __launch_bounds__(256) void prep_kernel(
    const float* __restrict__ w_attn, const float* __restrict__ w_proj,
    const float* __restrict__ x,
    unsigned short* __restrict__ waT, unsigned short* __restrict__ wpT,
    unsigned short* __restrict__ xb) {
  __shared__ float tile[32][33];
  const int z = blockIdx.z;
  if (z == 2) {
    const int id = blockIdx.y * 96 + blockIdx.x;
    if (id >= 2048) return;
    int i = (id * 256 + threadIdx.x) * 8;
    float4 f0 = *(const float4*)(x + i);
    float4 f1 = *(const float4*)(x + i + 4);
    union { unsigned short u[8]; uint4 v; } p;
    p.u[0] = f2bf(f0.x); p.u[1] = f2bf(f0.y); p.u[2] = f2bf(f0.z); p.u[3] = f2bf(f0.w);
    p.u[4] = f2bf(f1.x); p.u[5] = f2bf(f1.y); p.u[6] = f2bf(f1.z); p.u[7] = f2bf(f1.w);
    *(uint4*)(xb + i) = p.v;
    return;
  }
  const float* W;
  unsigned short* WT;
  int Kd, Nd;
  if (z == 0) { W = w_attn; WT = waT; Kd = 1024; Nd = 3072; }
  else {
    if (blockIdx.x >= 32) return;
    W = w_proj; WT = wpT; Kd = 1024; Nd = 1024;
  }
  const int n0 = blockIdx.x * 32, k0 = blockIdx.y * 32;
  const int tx = threadIdx.x & 31, ty = threadIdx.x >> 5;  // ty 0..7
#pragma unroll
  for (int i = 0; i < 4; ++i)
    tile[ty + i * 8][tx] = W[(size_t)(k0 + ty + i * 8) * Nd + n0 + tx];
  __syncthreads();
#pragma unroll
  for (int i = 0; i < 4; ++i)
    WT[(size_t)(n0 + ty + i * 8) * Kd + k0 + tx] = f2bf(tile[tx][ty + i * 8]);
}

// ---------------------------------------------------------------------------
// MFMA GEMM: C = A(bf16)[M,K] @ BT(bf16)[N,K]^T + bias.
// 128x128 tile, BK=64, 4 waves, m97 staging (verified).
// OUT_PLANES=1:
//   q/k planes: RoPE fused (HW trig, v10-verified) -> LDS -> 8x uint4 stores.
//   v plane (pl==2): direct transposed store to vT (verified v13).
// OUT_PLANES=0: fp32 out via two 64-row LDS passes, 8x float4 stores.
// ---------------------------------------------------------------------------
template <int OUT_PLANES>
__global__ __launch_bounds__(256) void mfma_gemm(
    const unsigned short* __restrict__ A,
    const unsigned short* __restrict__ BT,
    const float* __restrict__ bias,
    unsigned short* __restrict__ qP, unsigned short* __restrict__ kP,
    unsigned short* __restrict__ vT, float* __restrict__ Fout,
    int N, int K) {
  __shared__ unsigned short S[128 * 128];   // loop: As|Bs; epilogue: staging
  unsigned short* As = S;
  unsigned short* Bs = S + 128 * 64;

  const int tid = threadIdx.x;
  const int w = tid >> 6, lane = tid & 63;
  const int lo = lane & 15, g = lane >> 4;
  const int wm = (w >> 1) * 64, wn = (w & 1) * 64;
  const int m0 = blockIdx.y * 128, n0 = blockIdx.x * 128;

  const int lr8 = lane >> 3;           // row within the 8-row instr span

  const f32x4 zero4 = {0.f, 0.f, 0.f, 0.f};
  f32x4 acc[4][4] = {{zero4, zero4, zero4, zero4}, {zero4, zero4, zero4, zero4},
                     {zero4, zero4, zero4, zero4}, {zero4, zero4, zero4, zero4}};

  for (int k0 = 0; k0 < K; k0 += 64) {
    __syncthreads();  // previous iteration's frag readers done
#pragma unroll
    for (int it = 0; it < 4; ++it) {
      const int base_row = w * 32 + it * 8;       // wave-uniform
      const int r = base_row + lr8;               // this lane's row
      const int j = (lane & 7) ^ (r & 7);         // global chunk for LDS chunk lane&7
      gl_lds16(A + (size_t)(m0 + r) * K + k0 + j * 8, &As[base_row * 64]);
      gl_lds16(BT + (size_t)(n0 + r) * K + k0 + j * 8, &Bs[base_row * 64]);
    }
    __syncthreads();  // drains vmcnt -> staging visible

#pragma unroll
    for (int kk = 0; kk < 2; ++kk) {
      bf16x8 af[4], bfr[4];
#pragma unroll
      for (int i = 0; i < 4; ++i) {
        int ra = wm + i * 16 + lo;
        int rb = wn + i * 16 + lo;
        af[i]  = *(const bf16x8*)&As[ra * 64 + ((g + kk * 4) ^ (ra & 7)) * 8];
        bfr[i] = *(const bf16x8*)&Bs[rb * 64 + ((g + kk * 4) ^ (rb & 7)) * 8];
      }
#pragma unroll
      for (int i = 0; i < 4; ++i)
#pragma unroll
        for (int j = 0; j < 4; ++j)
          acc[i][j] = __builtin_amdgcn_mfma_f32_16x16x32_bf16(af[i], bfr[j],
                                                              acc[i][j], 0, 0, 0);
    }
  }

  float bv[4];
#pragma unroll
  for (int j = 0; j < 4; ++j) bv[j] = bias[n0 + wn + j * 16 + lo];

  if (OUT_PLANES) {
    const int pl = n0 >> 10;
    if (pl == 2) {
      // ---- v plane: direct transposed store to vT (verified v13)
      const int b = m0 >> 11;                  // uniform per block
      const int t0base = m0 & 2047;
      const int colbase = (n0 & 1023) + wn + lo;
#pragma unroll
      for (int i = 0; i < 4; ++i) {
        const int tt = t0base + wm + i * 16 + g * 4;
#pragma unroll
        for (int j = 0; j < 4; ++j) {
          const int col = colbase + j * 16;
          unsigned int u0 = (unsigned int)f2bf(acc[i][j][0] + bv[j]) |
                            ((unsigned int)f2bf(acc[i][j][1] + bv[j]) << 16);
          unsigned int u1 = (unsigned int)f2bf(acc[i][j][2] + bv[j]) |
                            ((unsigned int)f2bf(acc[i][j][3] + bv[j]) << 16);
          uint2 pw; pw.x = u0; pw.y = u1;
          *(uint2*)(vT + ((size_t)(b * 1024 + col)) * 2048 + tt) = pw;
        }
      }
    } else {
      __syncthreads();  // all frag readers done; S reusable
      // ---- q/k planes: fused RoPE (HW trig in revolutions; v10-verified)
      const float scale = (pl == 0) ? 0.125f : 1.0f;
      const float invA = exp2f((float)(-2 * lo) * (13.287712379549449f / 64.0f)) *
                         0.15915494309189535f;
      const float invB = exp2f((float)(-2 * (lo + 16)) * (13.287712379549449f / 64.0f)) *
                         0.15915494309189535f;
      const int c0 = wn + lo;
#pragma unroll
      for (int i = 0; i < 4; ++i)
#pragma unroll
        for (int r = 0; r < 4; ++r) {
          const int row = wm + i * 16 + g * 4 + r;
          const float t = (float)((m0 + row) & (T_ - 1));
          float ra = t * invA; ra -= floorf(ra);    // [0,1) revolutions
          float rb = t * invB; rb -= floorf(rb);
          const float sA = __builtin_amdgcn_sinf(ra);
          const float cA = __builtin_amdgcn_cosf(ra);
          const float sB = __builtin_amdgcn_sinf(rb);
          const float cB = __builtin_amdgcn_cosf(rb);
          const float q1A = acc[i][0][r] + bv[0];
          const float q2A = acc[i][2][r] + bv[2];
          const float q1B = acc[i][1][r] + bv[1];
          const float q2B = acc[i][3][r] + bv[3];
          S[row * 128 + c0]      = f2bf((q1A * cA - q2A * sA) * scale);
          S[row * 128 + c0 + 32] = f2bf((q2A * cA + q1A * sA) * scale);
          S[row * 128 + c0 + 16] = f2bf((q1B * cB - q2B * sB) * scale);
          S[row * 128 + c0 + 48] = f2bf((q2B * cB + q1B * sB) * scale);
        }
      __syncthreads();
      // ---- vectorized store: 8x uint4/thread, coalesced
      unsigned short* P = (pl == 0) ? qP : kP;
      const int pcol0 = n0 & 1023;
#pragma unroll
      for (int it2 = 0; it2 < 8; ++it2) {
        const int p = it2 * 256 + tid;          // uint4 index 0..2047
        const int lrow = p >> 4;                // 128 rows x 16 uint4
        const int lcol = (p & 15) * 8;
        uint4 v4 = *(const uint4*)&S[lrow * 128 + lcol];
        *(uint4*)(P + (size_t)(m0 + lrow) * 1024 + pcol0 + lcol) = v4;
      }
    }
  } else {
    // ---- fp32 out via two 64-row LDS passes (S as float[64][128])
    float* Sf = (float*)S;
#pragma unroll
    for (int hh = 0; hh < 2; ++hh) {
      __syncthreads();
      if ((w >> 1) == hh) {
#pragma unroll
        for (int i = 0; i < 4; ++i)
#pragma unroll
          for (int r = 0; r < 4; ++r) {
            const int lrow = i * 16 + g * 4 + r;
#pragma unroll
            for (int j = 0; j < 4; ++j)
              Sf[lrow * 128 + wn + j * 16 + lo] = acc[i][j][r] + bv[j];
          }
      }
      __syncthreads();
#pragma unroll
      for (int it2 = 0; it2 < 8; ++it2) {
        const int p = it2 * 256 + tid;        // float4 index 0..2047
        const int lrow = p >> 5;              // 64 rows x 32 float4
        const int lcol = (p & 31) * 4;
        float4 v4 = *(const float4*)&Sf[lrow * 128 + lcol];
        *(float4*)(Fout + (size_t)(m0 + hh * 64 + lrow) * N + n0 + lcol) = v4;
      }
    }
  }
}

// ---------------------------------------------------------------------------
// flash K/V staging: gl_lds16 with pre-swizzled global source (GEMM idiom,
// PMC-verified conflict-free). Tile = 64 rows x 64 bf16 (128B); wave w covers
// rows w*16+it*8; lane lands at LDS chunk lane&7, fetching global chunk
// (lane&7)^(r&7). LDS dest is wave-uniform base + lane*16 (HW rule).
// ---------------------------------------------------------------------------
static __device__ __forceinline__ void flash_stage(
    const unsigned short* kbase, const unsigned short* vbase,
    unsigned short* Kbuf, unsigned short* Vbuf,
    int kt, int w, int lr8, int lc8) {
#pragma unroll
  for (int it = 0; it < 2; ++it) {
    const int base = w * 16 + it * 8;        // wave-uniform
    const int r = base + lr8;                // this lane's row
    const int j = lc8 ^ (r & 7);             // global chunk for LDS chunk lc8
    gl_lds16(kbase + (size_t)(kt * 64 + r) * 1024 + j * 8, Kbuf + base * 64);
    gl_lds16(vbase + (size_t)r * 2048 + kt * 64 + j * 8, Vbuf + base * 64);
  }
}

// ---------------------------------------------------------------------------
// flash v14: verified compute core (paired tiles, swapped QK^T, b64 P-write,
// scalar lsum, setprio, XCD-chunked grid) with restructured staging:
//  * K/V via gl_lds16 double-buffer [2][64*64] linear, XOR-swizzled source
//    (replaces 4 global loads + 4 ds_write_b128 per wave-iter + the [72] pad).
//  * T3 minimum 2-phase: STAGE(buf^1,kt+1) -> compute(buf) -> vmcnt(0) ->
//    s_barrier. ONE barrier/iter (was 2). Hazards: STAGE at kt writes buf^1,
//    last read at kt-1, protected by kt-1's barrier; kt+1 reads after kt's
//    vmcnt(0)+barrier. Raw-barrier+vmcnt idiom HW-verified by v12's qkv pass.
//  * frag reads at chunk (g|4+g)^(r&7): 2 lanes/bank max (free, m136).
//  * Ps stays [64][72] padded (its reads need the pad), b64 writes.
// ---------------------------------------------------------------------------
__global__ __launch_bounds__(256) void flash_v14(
    unsigned short* __restrict__ qP,
    const unsigned short* __restrict__ kP,
    const unsigned short* __restrict__ vT) {
  const int cid = blockIdx.x;            // 0..511
  const int xcd = cid & 7;
  const int k6 = cid >> 3;               // 0..63
  const int bh = xcd * 4 + (k6 >> 4);    // 4 bh per XCD
  const int bx = k6 & 15;                // 0..15
  const int b = bh >> 4, h = bh & 15;
  const int tid = threadIdx.x;
  const int w = tid >> 6, lane = tid & 63;
  const int lo = lane & 15, g = lane >> 4;
  const int lr8 = lane >> 3, lc8 = lane & 7;

  __shared__ unsigned short Ks[2][64 * 64];   // [buf][key*64 + d-chunked]
  __shared__ unsigned short VTs[2][64 * 64];  // [buf][d*64 + key-chunked]
  __shared__ unsigned short Ps[64][72];       // [q][key], padded

  const f32x4 zero4 = {0.f, 0.f, 0.f, 0.f};

  const unsigned short* kbase = kP + (size_t)b * T_ * 1024 + h * 64;
  const unsigned short* vbase = vT + (size_t)bh * 64 * 2048;

#pragma unroll
  for (int half = 0; half < 2; ++half) {
    const int qt = half ? (31 - bx) : bx;
    const int rowq0 = b * T_ + qt * 64;

    // Q fragments for this wave's 16 q-rows (B-operand of swapped QK).
    const unsigned short* qrow = qP + (size_t)(rowq0 + w * 16 + lo) * 1024 + h * 64;
    bf16x8 aq0 = *(const bf16x8*)(qrow + g * 8);
    bf16x8 aq1 = *(const bf16x8*)(qrow + 32 + g * 8);

    f32x4 oacc[4] = {zero4, zero4, zero4, zero4};  // O[q=w*16+g*4+r][d=c2*16+lo]
    float lsum = 0.f;                              // denom partial, q = w*16+lo

    // prologue: tile 0 -> buf 0 (prior half's last barrier protects reuse)
    flash_stage(kbase, vbase, Ks[0], VTs[0], 0, w, lr8, lc8);
    asm volatile("s_waitcnt vmcnt(0)" ::: "memory");
    __builtin_amdgcn_sched_barrier(0);
    __builtin_amdgcn_s_barrier();

    for (int kt = 0; kt <= qt; ++kt) {
      const int buf = kt & 1;
      if (kt < qt)
        flash_stage(kbase, vbase, Ks[buf ^ 1], VTs[buf ^ 1], kt + 1, w, lr8, lc8);

      // ---- swapped QK^T: sacc[ct][r] = S^T[k=ct*16+g*4+r][q=w*16+lo]
      f32x4 sacc[4] = {zero4, zero4, zero4, zero4};
      __builtin_amdgcn_s_setprio(1);
#pragma unroll
      for (int ct = 0; ct < 4; ++ct) {
        const int r = ct * 16 + lo;
        bf16x8 bk0 = *(const bf16x8*)&Ks[buf][r * 64 + ((g)     ^ (r & 7)) * 8];
        bf16x8 bk1 = *(const bf16x8*)&Ks[buf][r * 64 + ((g + 4) ^ (r & 7)) * 8];
        sacc[ct] = __builtin_amdgcn_mfma_f32_16x16x32_bf16(bk0, aq0, sacc[ct], 0, 0, 0);
        sacc[ct] = __builtin_amdgcn_mfma_f32_16x16x32_bf16(bk1, aq1, sacc[ct], 0, 0, 0);
      }
      __builtin_amdgcn_s_setprio(0);

      // ---- causal mask (diagonal tile only): local k > local q -> -inf
      if (kt == qt) {
#pragma unroll
        for (int ct = 0; ct < 4; ++ct)
#pragma unroll
          for (int r = 0; r < 4; ++r)
            if (ct * 16 + g * 4 + r > w * 16 + lo) sacc[ct][r] = -1e30f;
      }

      // ---- exp + lsum + vectorized P-write (k consecutive in-lane)
#pragma unroll
      for (int ct = 0; ct < 4; ++ct) {
        float p0 = __expf(sacc[ct][0]);
        float p1 = __expf(sacc[ct][1]);
        float p2 = __expf(sacc[ct][2]);
        float p3 = __expf(sacc[ct][3]);
        lsum += (p0 + p1) + (p2 + p3);
        unsigned int u0 = (unsigned int)f2bf(p0) | ((unsigned int)f2bf(p1) << 16);
        unsigned int u1 = (unsigned int)f2bf(p2) | ((unsigned int)f2bf(p3) << 16);
        uint2 pw; pw.x = u0; pw.y = u1;
        *(uint2*)&Ps[w * 16 + lo][ct * 16 + g * 4] = pw;
      }

      // ---- PV (same-wave Ps write->read, in-order DS pipe)
      bf16x8 ap0 = *(const bf16x8*)&Ps[w * 16 + lo][g * 8];
      bf16x8 ap1 = *(const bf16x8*)&Ps[w * 16 + lo][32 + g * 8];
      __builtin_amdgcn_s_setprio(1);
#pragma unroll
      for (int c2 = 0; c2 < 4; ++c2) {
        const int r = c2 * 16 + lo;
        bf16x8 bv0 = *(const bf16x8*)&VTs[buf][r * 64 + ((g)     ^ (r & 7)) * 8];
        bf16x8 bv1 = *(const bf16x8*)&VTs[buf][r * 64 + ((g + 4) ^ (r & 7)) * 8];
        oacc[c2] = __builtin_amdgcn_mfma_f32_16x16x32_bf16(ap0, bv0, oacc[c2], 0, 0, 0);
        oacc[c2] = __builtin_amdgcn_mfma_f32_16x16x32_bf16(ap1, bv1, oacc[c2], 0, 0, 0);
      }
      __builtin_amdgcn_s_setprio(0);

      // ---- end of phase: prefetch landed + all waves' reads of buf done
      asm volatile("s_waitcnt vmcnt(0)" ::: "memory");
      __builtin_amdgcn_sched_barrier(0);
      __builtin_amdgcn_s_barrier();
    }

    // ---- denominator: reduce over g (lanes with same lo), then per-r pickup
    lsum += __shfl_xor(lsum, 16);
    lsum += __shfl_xor(lsum, 32);   // lanes {lo,lo+16,lo+32,lo+48}: full denom

#pragma unroll
    for (int r = 0; r < 4; ++r) {
      float inv_r = 1.0f / __shfl(lsum, g * 4 + r);  // lane s holds q=w*16+s
      unsigned short* dst = qP + (size_t)(rowq0 + w * 16 + g * 4 + r) * 1024 + h * 64 + lo;
#pragma unroll
      for (int c2 = 0; c2 < 4; ++c2)
        dst[c2 * 16] = f2bf(oacc[c2][r] * inv_r);
    }
    // last iter's barrier protects LDS reuse by next half's prologue stage
  }
}

// ---------------------------------------------------------------------------
extern "C" void kernel_launch(void* const* d_in, const int* in_sizes, int n_in,
                              void* d_out, int out_size, void* d_ws, size_t ws_size,
                              hipStream_t stream) {
  const float *x = nullptr, *w_attn = nullptr, *b_attn = nullptr,
              *w_proj = nullptr, *b_proj = nullptr;
  for (int i = 0; i < n_in; ++i) {
    switch (in_sizes[i]) {
      case B_ * T_ * C_:  x      = (const float*)d_in[i]; break;
      case C_ * 3 * C_:   w_attn = (const float*)d_in[i]; break;
      case 3 * C_:        b_attn = (const float*)d_in[i]; break;
      case C_ * C_:       w_proj = (const float*)d_in[i]; break;
      case C_:            b_proj = (const float*)d_in[i]; break;
      default: break;
    }
  }
  float* out = (float*)d_out;
  const int nblk = (out_size + 255) / 256;

  if (!x || !w_attn || !b_attn || !w_proj || !b_proj) {
    fill_kernel_f32<<<nblk, 256, 0, stream>>>(out, out_size, 100.0f);  // SENTINEL
    return;
  }
  // ws >= 48 MB proven (rounds 10/11 fast path). Sentinel otherwise.
  if (ws_size < (size_t)48 * 1024 * 1024) {
    fill_kernel_f32<<<nblk, 256, 0, stream>>>(out, out_size, 50.0f);   // SENTINEL
    return;
  }

  // layout: q|k planes (16 MB) | vP slot (8, unused) | vT (8) | xb (8) |
  //         waT (6) | wpT (2) = 48 MB
  unsigned short* qP  = (unsigned short*)d_ws;
  unsigned short* kP  = qP + (size_t)(B_ * T_) * 1024;
  unsigned short* vP  = kP + (size_t)(B_ * T_) * 1024;   // unused (kept for layout)
  unsigned short* vT  = vP + (size_t)(B_ * T_) * 1024;
  unsigned short* xb  = vT + (size_t)(B_ * T_) * 1024;
  unsigned short* waT = xb + (size_t)(B_ * T_) * C_;
  unsigned short* wpT = waT + (size_t)C_ * 3 * C_;
  (void)vP;

  // 0) fused prep: weight transposes + x conversion
  prep_kernel<<<dim3(96, 32, 3), 256, 0, stream>>>(w_attn, w_proj, x, waT, wpT, xb);
  // 1) qkv = xb @ w_attn + b_attn; RoPE fused (q/k), V transposed-stored to vT
  mfma_gemm<1><<<dim3((3 * C_) / 128, (B_ * T_) / 128), 256, 0, stream>>>(
      xb, waT, b_attn, qP, kP, vT, nullptr, 3 * C_, C_);
  // 2) causal flash attention v14 (gl_lds staging, 1 barrier/iter)
  flash_v14<<<dim3(512), 256, 0, stream>>>(qP, kP, vT);
  // 3) out = y @ w_proj + b_proj (fp32 out, vectorized epilogue)
  mfma_gemm<0><<<dim3(C_ / 128, (B_ * T_) / 128), 256, 0, stream>>>(
      qP, wpT, b_proj, nullptr, nullptr, nullptr, out, C_, C_);
}